// Round 1
// baseline (1627.675 us; speedup 1.0000x reference)
//
#include <hip/hip_runtime.h>
#include <hip/hip_bf16.h>

// Problem constants (from reference setup_inputs)
#define B_    8
#define N_    8192
#define C_    512
#define H_    8
#define HD_   64
#define M_    (B_ * N_)      // 65536 rows
#define TWO_C 1024

__device__ __forceinline__ float bf2f(unsigned v) {
    return __uint_as_float(v << 16);
}

// ---------------------------------------------------------------------------
// Kernel 1: qk = x @ qk_w^T + qk_b ; q = elu(qk[:,:C])+1 ; k = elu(qk[:,C:])+1
// Classic 64x64 LDS-tiled fp32 GEMM, 4x4 micro-tile per thread, BK=16.
// Writes q,k as bf16 into workspace (halves ws + later-stage traffic;
// numeric impact << 2%-of-max threshold).
// ---------------------------------------------------------------------------
__global__ __launch_bounds__(256) void gemm_qk_elu(
    const float* __restrict__ x, const float* __restrict__ w,
    const float* __restrict__ bias,
    __hip_bfloat16* __restrict__ qws, __hip_bfloat16* __restrict__ kws)
{
    __shared__ float as[16][64];   // [k][m]
    __shared__ float bs[16][64];   // [k][o]
    const int t  = threadIdx.x;
    const int m0 = blockIdx.y * 64;
    const int o0 = blockIdx.x * 64;
    const int tm = t >> 4, tn = t & 15;
    const int lr = t >> 2;          // 0..63 (row within tile for loads)
    const int lk = (t & 3) * 4;     // k offset (float4) for loads

    float acc[4][4];
#pragma unroll
    for (int i = 0; i < 4; i++)
#pragma unroll
        for (int j = 0; j < 4; j++) acc[i][j] = 0.f;

    for (int k0 = 0; k0 < C_; k0 += 16) {
        float4 av = *(const float4*)&x[(size_t)(m0 + lr) * C_ + k0 + lk];
        float4 bv = *(const float4*)&w[(size_t)(o0 + lr) * C_ + k0 + lk];
        __syncthreads();   // previous iteration's readers done
        as[lk + 0][lr] = av.x; as[lk + 1][lr] = av.y;
        as[lk + 2][lr] = av.z; as[lk + 3][lr] = av.w;
        bs[lk + 0][lr] = bv.x; bs[lk + 1][lr] = bv.y;
        bs[lk + 2][lr] = bv.z; bs[lk + 3][lr] = bv.w;
        __syncthreads();
#pragma unroll
        for (int kk = 0; kk < 16; kk++) {
            float4 a = *(const float4*)&as[kk][tm * 4];
            float4 b = *(const float4*)&bs[kk][tn * 4];
            float ar[4] = {a.x, a.y, a.z, a.w};
            float br[4] = {b.x, b.y, b.z, b.w};
#pragma unroll
            for (int i = 0; i < 4; i++)
#pragma unroll
                for (int j = 0; j < 4; j++) acc[i][j] += ar[i] * br[j];
        }
    }

    // Epilogue: bias + (elu + 1), split into q / k halves.
    // o0 is 64-aligned and C_=512 is a multiple of 64 -> branch is block-uniform.
#pragma unroll
    for (int i = 0; i < 4; i++) {
        const int m = m0 + tm * 4 + i;
#pragma unroll
        for (int j = 0; j < 4; j++) {
            const int o = o0 + tn * 4 + j;
            float v = acc[i][j] + bias[o];
            v = (v > 0.f) ? (v + 1.f) : __expf(v);   // elu(v)+1
            if (o < C_) qws[(size_t)m * C_ + o]        = __float2bfloat16(v);
            else        kws[(size_t)m * C_ + (o - C_)] = __float2bfloat16(v);
        }
    }
}

// ---------------------------------------------------------------------------
// Kernel 2: per (b,h): kv[d][e] = sum_n k[n,d]*v[n,e]  (v = x head-sliced)
//           kmean[d] = mean_n k[n,d]
// 64 blocks (one per b,h), 256 threads, 4x4 outputs/thread, N staged in
// 32-row LDS tiles.
// ---------------------------------------------------------------------------
__global__ __launch_bounds__(256) void kv_kernel(
    const __hip_bfloat16* __restrict__ kws, const float* __restrict__ x,
    float* __restrict__ kv, float* __restrict__ kmean)
{
    __shared__ float kt[32][64];
    __shared__ float vt[32][64];
    const int t  = threadIdx.x;
    const int bh = blockIdx.x;
    const int b  = bh >> 3, h = bh & 7;
    const int td = t >> 4, te = t & 15;
    const int kr = t >> 3;           // 0..31 row for k loads
    const int kc = (t & 7) * 8;      // 8-wide bf16 col
    const int vr = t >> 4;           // 0..15 (rows vr, vr+16) for v loads
    const int vc = (t & 15) * 4;     // float4 col

    const size_t base = (size_t)b * N_ * C_ + h * HD_;

    float acc[4][4];
    float ksum[4] = {0.f, 0.f, 0.f, 0.f};
#pragma unroll
    for (int i = 0; i < 4; i++)
#pragma unroll
        for (int j = 0; j < 4; j++) acc[i][j] = 0.f;

    for (int n0 = 0; n0 < N_; n0 += 32) {
        uint4  ku = *(const uint4*)&kws[base + (size_t)(n0 + kr) * C_ + kc];
        float4 v0 = *(const float4*)&x[base + (size_t)(n0 + vr) * C_ + vc];
        float4 v1 = *(const float4*)&x[base + (size_t)(n0 + vr + 16) * C_ + vc];
        __syncthreads();
        kt[kr][kc + 0] = bf2f(ku.x & 0xffffu); kt[kr][kc + 1] = bf2f(ku.x >> 16);
        kt[kr][kc + 2] = bf2f(ku.y & 0xffffu); kt[kr][kc + 3] = bf2f(ku.y >> 16);
        kt[kr][kc + 4] = bf2f(ku.z & 0xffffu); kt[kr][kc + 5] = bf2f(ku.z >> 16);
        kt[kr][kc + 6] = bf2f(ku.w & 0xffffu); kt[kr][kc + 7] = bf2f(ku.w >> 16);
        *(float4*)&vt[vr][vc]      = v0;
        *(float4*)&vt[vr + 16][vc] = v1;
        __syncthreads();
#pragma unroll
        for (int nn = 0; nn < 32; nn++) {
            float4 kd = *(const float4*)&kt[nn][td * 4];
            float4 ve = *(const float4*)&vt[nn][te * 4];
            float kr4[4] = {kd.x, kd.y, kd.z, kd.w};
            float vr4[4] = {ve.x, ve.y, ve.z, ve.w};
#pragma unroll
            for (int i = 0; i < 4; i++)
#pragma unroll
                for (int j = 0; j < 4; j++) acc[i][j] += kr4[i] * vr4[j];
            // all threads accumulate (uniform per td) -> no divergence
            ksum[0] += kd.x; ksum[1] += kd.y; ksum[2] += kd.z; ksum[3] += kd.w;
        }
    }

    float* kvp = kv + (size_t)bh * HD_ * HD_;
#pragma unroll
    for (int i = 0; i < 4; i++)
#pragma unroll
        for (int j = 0; j < 4; j++)
            kvp[(td * 4 + i) * HD_ + te * 4 + j] = acc[i][j];
    if (te == 0) {
#pragma unroll
        for (int i = 0; i < 4; i++)
            kmean[bh * HD_ + td * 4 + i] = ksum[i] * (1.0f / N_);
    }
}

// ---------------------------------------------------------------------------
// Kernel 3: out[b,n,h*64+e] = z[n] * sum_d q[n,d]*kv[d,e] + lepe(x)
// grid (N/64, B*H); 64 token-rows x 64 channels per block.
// ---------------------------------------------------------------------------
__global__ __launch_bounds__(256) void out_kernel(
    const __hip_bfloat16* __restrict__ qws, const float* __restrict__ x,
    const float* __restrict__ kv, const float* __restrict__ kmean,
    const float* __restrict__ lw, const float* __restrict__ lb,
    float* __restrict__ out)
{
    __shared__ float kvs[64][64];
    __shared__ float qs[64][65];   // +1 pad: conflict-free strided row reads
    __shared__ float xs[66][64];   // rows n0-1 .. n0+64
    __shared__ float zz[64];
    __shared__ float kms[64];
    __shared__ float lws[64][3];
    __shared__ float lbs[64];

    const int t  = threadIdx.x;
    const int n0 = blockIdx.x * 64;
    const int bh = blockIdx.y;
    const int b  = bh >> 3, h = bh & 7;

    // kv tile: 4096 floats = 1024 float4
    {
        const float* kvp = kv + (size_t)bh * 4096;
        for (int i = t; i < 1024; i += 256) {
            const int r = i >> 4, c4 = (i & 15) * 4;
            *(float4*)&kvs[r][c4] = *(const float4*)&kvp[r * 64 + c4];
        }
    }
    // q tile: 64x64 bf16 = 512 8-elem chunks
    {
        const __hip_bfloat16* qp = &qws[((size_t)b * N_ + n0) * C_ + h * HD_];
        for (int i = t; i < 512; i += 256) {
            const int r = i >> 3, c8 = (i & 7) * 8;
            uint4 u = *(const uint4*)&qp[(size_t)r * C_ + c8];
            qs[r][c8 + 0] = bf2f(u.x & 0xffffu); qs[r][c8 + 1] = bf2f(u.x >> 16);
            qs[r][c8 + 2] = bf2f(u.y & 0xffffu); qs[r][c8 + 3] = bf2f(u.y >> 16);
            qs[r][c8 + 4] = bf2f(u.z & 0xffffu); qs[r][c8 + 5] = bf2f(u.z >> 16);
            qs[r][c8 + 6] = bf2f(u.w & 0xffffu); qs[r][c8 + 7] = bf2f(u.w >> 16);
        }
    }
    // x tile for lepe: 66 rows x 64 cols = 1056 float4 (zero-padded at edges)
    {
        for (int i = t; i < 1056; i += 256) {
            const int r = i >> 4, c4 = (i & 15) * 4;
            const int n = n0 - 1 + r;
            float4 v = make_float4(0.f, 0.f, 0.f, 0.f);
            if (n >= 0 && n < N_)
                v = *(const float4*)&x[((size_t)b * N_ + n) * C_ + h * HD_ + c4];
            *(float4*)&xs[r][c4] = v;
        }
    }
    if (t < 64) {
        const int c = h * HD_ + t;
        lws[t][0] = lw[c * 3 + 0];
        lws[t][1] = lw[c * 3 + 1];
        lws[t][2] = lw[c * 3 + 2];
        lbs[t] = lb[c];
        kms[t] = kmean[bh * HD_ + t];
    }
    __syncthreads();

    // z[n] = 1 / (q[n,:] . kmean + 1e-6)
    if (t < 64) {
        float s = 0.f;
        for (int d = 0; d < 64; d++) s += qs[t][d] * kms[d];
        zz[t] = 1.0f / (s + 1e-6f);
    }
    __syncthreads();

    const int tr = t >> 4, tc = t & 15;
    float acc[4][4];
#pragma unroll
    for (int i = 0; i < 4; i++)
#pragma unroll
        for (int j = 0; j < 4; j++) acc[i][j] = 0.f;

    for (int d = 0; d < 64; d++) {
        float4 kj = *(const float4*)&kvs[d][tc * 4];
        float kr4[4] = {kj.x, kj.y, kj.z, kj.w};
        float qi[4];
#pragma unroll
        for (int i = 0; i < 4; i++) qi[i] = qs[tr * 4 + i][d];
#pragma unroll
        for (int i = 0; i < 4; i++)
#pragma unroll
            for (int j = 0; j < 4; j++) acc[i][j] += qi[i] * kr4[j];
    }

#pragma unroll
    for (int i = 0; i < 4; i++) {
        const int nn = tr * 4 + i;
        const int n  = n0 + nn;
        const float z = zz[nn];
        const int e0 = tc * 4;
        float le[4];
#pragma unroll
        for (int j = 0; j < 4; j++) {
            const int e = e0 + j;
            le[j] = xs[nn][e]     * lws[e][0]
                  + xs[nn + 1][e] * lws[e][1]
                  + xs[nn + 2][e] * lws[e][2]
                  + lbs[e];
        }
        float4 o;
        o.x = acc[i][0] * z + le[0];
        o.y = acc[i][1] * z + le[1];
        o.z = acc[i][2] * z + le[2];
        o.w = acc[i][3] * z + le[3];
        *(float4*)&out[((size_t)b * N_ + n) * C_ + h * HD_ + e0] = o;
    }
}

// ---------------------------------------------------------------------------
extern "C" void kernel_launch(void* const* d_in, const int* in_sizes, int n_in,
                              void* d_out, int out_size, void* d_ws, size_t ws_size,
                              hipStream_t stream)
{
    const float* x      = (const float*)d_in[0];
    const float* qk_w   = (const float*)d_in[1];
    const float* qk_b   = (const float*)d_in[2];
    const float* lepe_w = (const float*)d_in[3];
    const float* lepe_b = (const float*)d_in[4];
    float* out = (float*)d_out;

    // Workspace layout (needs ~135.3 MB):
    //   q  bf16 [M, C]   67.1 MB
    //   k  bf16 [M, C]   67.1 MB
    //   kv f32  [64, 64, 64]  1 MB
    //   kmean f32 [64, 64]   16 KB
    char* ws = (char*)d_ws;
    __hip_bfloat16* qws = (__hip_bfloat16*)ws;
    __hip_bfloat16* kws = qws + (size_t)M_ * C_;
    float* kv    = (float*)(ws + 2 * (size_t)M_ * C_ * sizeof(__hip_bfloat16));
    float* kmean = kv + (size_t)64 * HD_ * HD_;

    gemm_qk_elu<<<dim3(TWO_C / 64, M_ / 64), 256, 0, stream>>>(
        x, qk_w, qk_b, qws, kws);
    kv_kernel<<<64, 256, 0, stream>>>(kws, x, kv, kmean);
    out_kernel<<<dim3(N_ / 64, B_ * H_), 256, 0, stream>>>(
        qws, x, kv, kmean, lepe_w, lepe_b, out);
}

// Round 2
// 561.128 us; speedup vs baseline: 2.9007x; 2.9007x over previous
//
#include <hip/hip_runtime.h>
#include <hip/hip_bf16.h>

// Problem constants (from reference setup_inputs)
#define B_    8
#define N_    8192
#define C_    512
#define H_    8
#define HD_   64
#define M_    (B_ * N_)      // 65536 rows
#define TWO_C 1024

typedef short short8 __attribute__((ext_vector_type(8)));   // 8 bf16 (4 VGPRs)
typedef float f32x4  __attribute__((ext_vector_type(4)));   // MFMA accumulator

__device__ __forceinline__ float bf2f(unsigned v) {
    return __uint_as_float(v << 16);
}

__device__ __forceinline__ unsigned f2bf(float f) {
    union { __hip_bfloat16 b; unsigned short u; } cv;
    cv.b = __float2bfloat16(f);
    return (unsigned)cv.u;
}

__device__ __forceinline__ uint2 pack4(float4 f) {
    uint2 r;
    r.x = f2bf(f.x) | (f2bf(f.y) << 16);
    r.y = f2bf(f.z) | (f2bf(f.w) << 16);
    return r;
}

// ---------------------------------------------------------------------------
// Kernel 1: qk = x @ qk_w^T + qk_b ; q = elu(.)+1 ; k = elu(.)+1  (bf16 out)
// MFMA bf16 GEMM: 128x128 block tile, BK=32, 256 thr (4 waves, 2x2 wave grid),
// each wave 4x4 tiles of 16x16x32. A,B staged regs->cvt->LDS (fp32 in global).
// Fragment layout (verified m89/m91): A/B lane ln holds row (ln&15),
// k = (ln>>4)*8 + j ; C/D: col = ln&15, row = (ln>>4)*4 + reg.
// ---------------------------------------------------------------------------
__global__ __launch_bounds__(256, 2) void gemm_qk_mfma(
    const float* __restrict__ x, const float* __restrict__ w,
    const float* __restrict__ bias,
    __hip_bfloat16* __restrict__ qws, __hip_bfloat16* __restrict__ kws)
{
    __shared__ __align__(16) unsigned short As[128 * 32];  // [row][k] bf16
    __shared__ __align__(16) unsigned short Bs[128 * 32];

    const int t  = threadIdx.x;
    const int wv = t >> 6;
    const int ln = t & 63;
    const int m0 = blockIdx.y * 128;
    const int n0 = blockIdx.x * 128;

    const int sr = t >> 2;            // staging row 0..63 (and +64)
    const int sk = (t & 3) * 8;       // staging k-offset (8 elems)

    const int wm = wv & 1, wn = wv >> 1;   // wave position in 2x2
    const int fr = ln & 15;                // fragment row / C-col
    const int fk = (ln >> 4) * 8;          // fragment k-offset

    f32x4 acc[4][4];
#pragma unroll
    for (int i = 0; i < 4; i++)
#pragma unroll
        for (int j = 0; j < 4; j++) acc[i][j] = {0.f, 0.f, 0.f, 0.f};

    const float* xa = x + (size_t)(m0 + sr) * C_ + sk;
    const float* wa = w + (size_t)(n0 + sr) * C_ + sk;

    for (int k0 = 0; k0 < C_; k0 += 32) {
        // issue global loads before the barrier (no LDS dependency yet)
        float4 a0 = *(const float4*)(xa + k0);
        float4 a1 = *(const float4*)(xa + k0 + 4);
        float4 a2 = *(const float4*)(xa + k0 + (size_t)64 * C_);
        float4 a3 = *(const float4*)(xa + k0 + (size_t)64 * C_ + 4);
        float4 b0 = *(const float4*)(wa + k0);
        float4 b1 = *(const float4*)(wa + k0 + 4);
        float4 b2 = *(const float4*)(wa + k0 + (size_t)64 * C_);
        float4 b3 = *(const float4*)(wa + k0 + (size_t)64 * C_ + 4);
        if (k0) __syncthreads();   // previous iteration's fragment reads done
        uint2 pa0 = pack4(a0), pa1 = pack4(a1), pa2 = pack4(a2), pa3 = pack4(a3);
        uint2 pb0 = pack4(b0), pb1 = pack4(b1), pb2 = pack4(b2), pb3 = pack4(b3);
        *(uint4*)&As[sr * 32 + sk]        = make_uint4(pa0.x, pa0.y, pa1.x, pa1.y);
        *(uint4*)&As[(sr + 64) * 32 + sk] = make_uint4(pa2.x, pa2.y, pa3.x, pa3.y);
        *(uint4*)&Bs[sr * 32 + sk]        = make_uint4(pb0.x, pb0.y, pb1.x, pb1.y);
        *(uint4*)&Bs[(sr + 64) * 32 + sk] = make_uint4(pb2.x, pb2.y, pb3.x, pb3.y);
        __syncthreads();

        short8 af[4], bfr[4];
#pragma unroll
        for (int i = 0; i < 4; i++)
            af[i] = *(const short8*)&As[(wm * 64 + i * 16 + fr) * 32 + fk];
#pragma unroll
        for (int j = 0; j < 4; j++)
            bfr[j] = *(const short8*)&Bs[(wn * 64 + j * 16 + fr) * 32 + fk];
#pragma unroll
        for (int i = 0; i < 4; i++)
#pragma unroll
            for (int j = 0; j < 4; j++)
                acc[i][j] = __builtin_amdgcn_mfma_f32_16x16x32_bf16(
                    af[i], bfr[j], acc[i][j], 0, 0, 0);
    }

    // Epilogue: bias + elu+1 -> bf16 q/k. n0 multiple of 128; C_=512 boundary
    // is tile-aligned -> q/k split is block-uniform.
    __hip_bfloat16* dst;
    int oc0;
    if (n0 < C_) { dst = qws; oc0 = n0; }
    else         { dst = kws; oc0 = n0 - C_; }
    float bv[4];
#pragma unroll
    for (int j = 0; j < 4; j++) bv[j] = bias[n0 + wn * 64 + j * 16 + fr];
    const int rb = (ln >> 4) * 4;
#pragma unroll
    for (int i = 0; i < 4; i++) {
#pragma unroll
        for (int r = 0; r < 4; r++) {
            const size_t m = (size_t)(m0 + wm * 64 + i * 16 + rb + r);
#pragma unroll
            for (int j = 0; j < 4; j++) {
                const int oc = oc0 + wn * 64 + j * 16 + fr;
                float v = acc[i][j][r] + bv[j];
                v = (v > 0.f) ? (v + 1.f) : __expf(v);   // elu(v)+1
                dst[m * C_ + oc] = __float2bfloat16(v);
            }
        }
    }
}

// ---------------------------------------------------------------------------
// Kernel 2: split-N partial kv + kmean, atomically accumulated.
// grid (16 N-chunks, 64 bh) = 1024 blocks; each handles 512 tokens.
// ---------------------------------------------------------------------------
__global__ __launch_bounds__(256) void kv_partial(
    const __hip_bfloat16* __restrict__ kws, const float* __restrict__ x,
    float* __restrict__ kv, float* __restrict__ kmean)
{
    __shared__ float kt[32][64];
    __shared__ float vt[32][64];
    const int t  = threadIdx.x;
    const int s  = blockIdx.x;       // N chunk 0..15
    const int bh = blockIdx.y;       // 0..63
    const int b  = bh >> 3, h = bh & 7;
    const int td = t >> 4, te = t & 15;
    const int kr = t >> 3;           // 0..31 row for k loads
    const int kc = (t & 7) * 8;      // 8-wide bf16 col
    const int vr = t >> 4;           // rows vr, vr+16 for v loads
    const int vc = (t & 15) * 4;     // float4 col

    const size_t base = (size_t)b * N_ * C_ + h * HD_;

    float acc[4][4];
    float ksum[4] = {0.f, 0.f, 0.f, 0.f};
#pragma unroll
    for (int i = 0; i < 4; i++)
#pragma unroll
        for (int j = 0; j < 4; j++) acc[i][j] = 0.f;

    const int nstart = s * (N_ / 16);
    for (int n0 = nstart; n0 < nstart + N_ / 16; n0 += 32) {
        uint4  ku = *(const uint4*)&kws[base + (size_t)(n0 + kr) * C_ + kc];
        float4 v0 = *(const float4*)&x[base + (size_t)(n0 + vr) * C_ + vc];
        float4 v1 = *(const float4*)&x[base + (size_t)(n0 + vr + 16) * C_ + vc];
        __syncthreads();
        kt[kr][kc + 0] = bf2f(ku.x & 0xffffu); kt[kr][kc + 1] = bf2f(ku.x >> 16);
        kt[kr][kc + 2] = bf2f(ku.y & 0xffffu); kt[kr][kc + 3] = bf2f(ku.y >> 16);
        kt[kr][kc + 4] = bf2f(ku.z & 0xffffu); kt[kr][kc + 5] = bf2f(ku.z >> 16);
        kt[kr][kc + 6] = bf2f(ku.w & 0xffffu); kt[kr][kc + 7] = bf2f(ku.w >> 16);
        *(float4*)&vt[vr][vc]      = v0;
        *(float4*)&vt[vr + 16][vc] = v1;
        __syncthreads();
#pragma unroll
        for (int nn = 0; nn < 32; nn++) {
            float4 kd = *(const float4*)&kt[nn][td * 4];
            float4 ve = *(const float4*)&vt[nn][te * 4];
            float kr4[4] = {kd.x, kd.y, kd.z, kd.w};
            float vr4[4] = {ve.x, ve.y, ve.z, ve.w};
#pragma unroll
            for (int i = 0; i < 4; i++)
#pragma unroll
                for (int j = 0; j < 4; j++) acc[i][j] += kr4[i] * vr4[j];
            ksum[0] += kd.x; ksum[1] += kd.y; ksum[2] += kd.z; ksum[3] += kd.w;
        }
    }

    float* kvp = kv + (size_t)bh * HD_ * HD_;
#pragma unroll
    for (int i = 0; i < 4; i++)
#pragma unroll
        for (int j = 0; j < 4; j++)
            atomicAdd(&kvp[(td * 4 + i) * HD_ + te * 4 + j], acc[i][j]);
    if (te == 0) {
#pragma unroll
        for (int i = 0; i < 4; i++)
            atomicAdd(&kmean[bh * HD_ + td * 4 + i], ksum[i] * (1.0f / N_));
    }
}

// ---------------------------------------------------------------------------
// Kernel 3: out[b,n,h*64+e] = z[n] * sum_d q[n,d]*kv[d,e] + lepe(x)
// grid (N/64, B*H); 64 token-rows x 64 channels per block.
// ---------------------------------------------------------------------------
__global__ __launch_bounds__(256) void out_kernel(
    const __hip_bfloat16* __restrict__ qws, const float* __restrict__ x,
    const float* __restrict__ kv, const float* __restrict__ kmean,
    const float* __restrict__ lw, const float* __restrict__ lb,
    float* __restrict__ out)
{
    __shared__ float kvs[64][64];
    __shared__ float qs[64][65];   // +1 pad: conflict-free strided row reads
    __shared__ float xs[66][64];   // rows n0-1 .. n0+64
    __shared__ float zz[64];
    __shared__ float kms[64];
    __shared__ float lws[64][3];
    __shared__ float lbs[64];

    const int t  = threadIdx.x;
    const int n0 = blockIdx.x * 64;
    const int bh = blockIdx.y;
    const int b  = bh >> 3, h = bh & 7;

    {
        const float* kvp = kv + (size_t)bh * 4096;
        for (int i = t; i < 1024; i += 256) {
            const int r = i >> 4, c4 = (i & 15) * 4;
            *(float4*)&kvs[r][c4] = *(const float4*)&kvp[r * 64 + c4];
        }
    }
    {
        const __hip_bfloat16* qp = &qws[((size_t)b * N_ + n0) * C_ + h * HD_];
        for (int i = t; i < 512; i += 256) {
            const int r = i >> 3, c8 = (i & 7) * 8;
            uint4 u = *(const uint4*)&qp[(size_t)r * C_ + c8];
            qs[r][c8 + 0] = bf2f(u.x & 0xffffu); qs[r][c8 + 1] = bf2f(u.x >> 16);
            qs[r][c8 + 2] = bf2f(u.y & 0xffffu); qs[r][c8 + 3] = bf2f(u.y >> 16);
            qs[r][c8 + 4] = bf2f(u.z & 0xffffu); qs[r][c8 + 5] = bf2f(u.z >> 16);
            qs[r][c8 + 6] = bf2f(u.w & 0xffffu); qs[r][c8 + 7] = bf2f(u.w >> 16);
        }
    }
    {
        for (int i = t; i < 1056; i += 256) {
            const int r = i >> 4, c4 = (i & 15) * 4;
            const int n = n0 - 1 + r;
            float4 v = make_float4(0.f, 0.f, 0.f, 0.f);
            if (n >= 0 && n < N_)
                v = *(const float4*)&x[((size_t)b * N_ + n) * C_ + h * HD_ + c4];
            *(float4*)&xs[r][c4] = v;
        }
    }
    if (t < 64) {
        const int c = h * HD_ + t;
        lws[t][0] = lw[c * 3 + 0];
        lws[t][1] = lw[c * 3 + 1];
        lws[t][2] = lw[c * 3 + 2];
        lbs[t] = lb[c];
        kms[t] = kmean[bh * HD_ + t];
    }
    __syncthreads();

    if (t < 64) {
        float s = 0.f;
        for (int d = 0; d < 64; d++) s += qs[t][d] * kms[d];
        zz[t] = 1.0f / (s + 1e-6f);
    }
    __syncthreads();

    const int tr = t >> 4, tc = t & 15;
    float acc[4][4];
#pragma unroll
    for (int i = 0; i < 4; i++)
#pragma unroll
        for (int j = 0; j < 4; j++) acc[i][j] = 0.f;

    for (int d = 0; d < 64; d++) {
        float4 kj = *(const float4*)&kvs[d][tc * 4];
        float kr4[4] = {kj.x, kj.y, kj.z, kj.w};
        float qi[4];
#pragma unroll
        for (int i = 0; i < 4; i++) qi[i] = qs[tr * 4 + i][d];
#pragma unroll
        for (int i = 0; i < 4; i++)
#pragma unroll
            for (int j = 0; j < 4; j++) acc[i][j] += qi[i] * kr4[j];
    }

#pragma unroll
    for (int i = 0; i < 4; i++) {
        const int nn = tr * 4 + i;
        const int n  = n0 + nn;
        const float z = zz[nn];
        const int e0 = tc * 4;
        float le[4];
#pragma unroll
        for (int j = 0; j < 4; j++) {
            const int e = e0 + j;
            le[j] = xs[nn][e]     * lws[e][0]
                  + xs[nn + 1][e] * lws[e][1]
                  + xs[nn + 2][e] * lws[e][2]
                  + lbs[e];
        }
        float4 o;
        o.x = acc[i][0] * z + le[0];
        o.y = acc[i][1] * z + le[1];
        o.z = acc[i][2] * z + le[2];
        o.w = acc[i][3] * z + le[3];
        *(float4*)&out[((size_t)b * N_ + n) * C_ + h * HD_ + e0] = o;
    }
}

// ---------------------------------------------------------------------------
extern "C" void kernel_launch(void* const* d_in, const int* in_sizes, int n_in,
                              void* d_out, int out_size, void* d_ws, size_t ws_size,
                              hipStream_t stream)
{
    const float* x      = (const float*)d_in[0];
    const float* qk_w   = (const float*)d_in[1];
    const float* qk_b   = (const float*)d_in[2];
    const float* lepe_w = (const float*)d_in[3];
    const float* lepe_b = (const float*)d_in[4];
    float* out = (float*)d_out;

    // Workspace (same 135.3 MB footprint as validated round 1):
    //   q  bf16 [M, C]   67.1 MB
    //   k  bf16 [M, C]   67.1 MB
    //   kv f32  [64, 64, 64]  1 MB   (atomic-accumulated, memset to 0)
    //   kmean f32 [64, 64]   16 KB   (contiguous with kv for one memset)
    char* ws = (char*)d_ws;
    __hip_bfloat16* qws = (__hip_bfloat16*)ws;
    __hip_bfloat16* kws = qws + (size_t)M_ * C_;
    float* kv    = (float*)(ws + 2 * (size_t)M_ * C_ * sizeof(__hip_bfloat16));
    float* kmean = kv + (size_t)64 * HD_ * HD_;

    hipMemsetAsync(kv, 0, (size_t)(64 * HD_ * HD_ + 64 * HD_) * sizeof(float),
                   stream);
    gemm_qk_mfma<<<dim3(TWO_C / 128, M_ / 128), 256, 0, stream>>>(
        x, qk_w, qk_b, qws, kws);
    kv_partial<<<dim3(16, 64), 256, 0, stream>>>(kws, x, kv, kmean);
    out_kernel<<<dim3(N_ / 64, B_ * H_), 256, 0, stream>>>(
        qws, x, kv, kmean, lepe_w, lepe_b, out);
}

// Round 3
// 531.124 us; speedup vs baseline: 3.0646x; 1.0565x over previous
//
#include <hip/hip_runtime.h>
#include <hip/hip_bf16.h>

// Problem constants (from reference setup_inputs)
#define B_    8
#define N_    8192
#define C_    512
#define H_    8
#define HD_   64
#define M_    (B_ * N_)      // 65536 rows
#define TWO_C 1024

typedef short short8 __attribute__((ext_vector_type(8)));   // 8 bf16 (4 VGPRs)
typedef float f32x4  __attribute__((ext_vector_type(4)));   // MFMA accumulator

__device__ __forceinline__ float bf2f(unsigned v) {
    return __uint_as_float(v << 16);
}

__device__ __forceinline__ unsigned f2bf(float f) {
    union { __hip_bfloat16 b; unsigned short u; } cv;
    cv.b = __float2bfloat16(f);
    return (unsigned)cv.u;
}

__device__ __forceinline__ uint2 pack4(float4 f) {
    uint2 r;
    r.x = f2bf(f.x) | (f2bf(f.y) << 16);
    r.y = f2bf(f.z) | (f2bf(f.w) << 16);
    return r;
}

// ---------------------------------------------------------------------------
// Kernel 1: qk = x @ qk_w^T + qk_b ; q = elu(.)+1 ; k = elu(.)+1  (bf16 out)
// MFMA bf16 GEMM: 128x128 tile, BK=32, 4 waves (2x2), 4x4 16x16x32 per wave.
// XCD swizzle: all 8 column tiles of a row panel land on the same XCD
// (xcd = L&7 = rp%8 under round-robin dispatch) so the x panel is fetched
// from HBM once and re-read from that XCD's L2. 8 panels * 256KB + w(2MB)
// fits the 4MB per-XCD L2.
// ---------------------------------------------------------------------------
__global__ __launch_bounds__(256, 2) void gemm_qk_mfma(
    const float* __restrict__ x, const float* __restrict__ w,
    const float* __restrict__ bias,
    __hip_bfloat16* __restrict__ qws, __hip_bfloat16* __restrict__ kws)
{
    __shared__ __align__(16) unsigned short As[128 * 32];  // [row][k] bf16
    __shared__ __align__(16) unsigned short Bs[128 * 32];

    const int t  = threadIdx.x;
    const int wv = t >> 6;
    const int ln = t & 63;

    // swizzled decode: L = xcd + 8*(cp + 8*(rp>>3)), rp%8 == xcd
    const int L  = blockIdx.x;
    const int rp = (L & 7) + ((L >> 6) << 3);   // row panel 0..511
    const int cp = (L >> 3) & 7;                // col tile  0..7
    const int m0 = rp * 128;
    const int n0 = cp * 128;

    const int sr = t >> 2;            // staging row 0..63 (and +64)
    const int sk = (t & 3) * 8;       // staging k-offset (8 elems)

    const int wm = wv & 1, wn = wv >> 1;   // wave position in 2x2
    const int fr = ln & 15;                // fragment row / C-col
    const int fk = (ln >> 4) * 8;          // fragment k-offset

    f32x4 acc[4][4];
#pragma unroll
    for (int i = 0; i < 4; i++)
#pragma unroll
        for (int j = 0; j < 4; j++) acc[i][j] = {0.f, 0.f, 0.f, 0.f};

    const float* xa = x + (size_t)(m0 + sr) * C_ + sk;
    const float* wa = w + (size_t)(n0 + sr) * C_ + sk;

    for (int k0 = 0; k0 < C_; k0 += 32) {
        float4 a0 = *(const float4*)(xa + k0);
        float4 a1 = *(const float4*)(xa + k0 + 4);
        float4 a2 = *(const float4*)(xa + k0 + (size_t)64 * C_);
        float4 a3 = *(const float4*)(xa + k0 + (size_t)64 * C_ + 4);
        float4 b0 = *(const float4*)(wa + k0);
        float4 b1 = *(const float4*)(wa + k0 + 4);
        float4 b2 = *(const float4*)(wa + k0 + (size_t)64 * C_);
        float4 b3 = *(const float4*)(wa + k0 + (size_t)64 * C_ + 4);
        if (k0) __syncthreads();
        uint2 pa0 = pack4(a0), pa1 = pack4(a1), pa2 = pack4(a2), pa3 = pack4(a3);
        uint2 pb0 = pack4(b0), pb1 = pack4(b1), pb2 = pack4(b2), pb3 = pack4(b3);
        *(uint4*)&As[sr * 32 + sk]        = make_uint4(pa0.x, pa0.y, pa1.x, pa1.y);
        *(uint4*)&As[(sr + 64) * 32 + sk] = make_uint4(pa2.x, pa2.y, pa3.x, pa3.y);
        *(uint4*)&Bs[sr * 32 + sk]        = make_uint4(pb0.x, pb0.y, pb1.x, pb1.y);
        *(uint4*)&Bs[(sr + 64) * 32 + sk] = make_uint4(pb2.x, pb2.y, pb3.x, pb3.y);
        __syncthreads();

        short8 af[4], bfr[4];
#pragma unroll
        for (int i = 0; i < 4; i++)
            af[i] = *(const short8*)&As[(wm * 64 + i * 16 + fr) * 32 + fk];
#pragma unroll
        for (int j = 0; j < 4; j++)
            bfr[j] = *(const short8*)&Bs[(wn * 64 + j * 16 + fr) * 32 + fk];
#pragma unroll
        for (int i = 0; i < 4; i++)
#pragma unroll
            for (int j = 0; j < 4; j++)
                acc[i][j] = __builtin_amdgcn_mfma_f32_16x16x32_bf16(
                    af[i], bfr[j], acc[i][j], 0, 0, 0);
    }

    __hip_bfloat16* dst;
    int oc0;
    if (n0 < C_) { dst = qws; oc0 = n0; }
    else         { dst = kws; oc0 = n0 - C_; }
    float bv[4];
#pragma unroll
    for (int j = 0; j < 4; j++) bv[j] = bias[n0 + wn * 64 + j * 16 + fr];
    const int rb = (ln >> 4) * 4;
#pragma unroll
    for (int i = 0; i < 4; i++) {
#pragma unroll
        for (int r = 0; r < 4; r++) {
            const size_t m = (size_t)(m0 + wm * 64 + i * 16 + rb + r);
#pragma unroll
            for (int j = 0; j < 4; j++) {
                const int oc = oc0 + wn * 64 + j * 16 + fr;
                float v = acc[i][j][r] + bv[j];
                v = (v > 0.f) ? (v + 1.f) : __expf(v);   // elu(v)+1
                dst[m * C_ + oc] = __float2bfloat16(v);
            }
        }
    }
}

// ---------------------------------------------------------------------------
// Kernel 2: split-N partial kv + kmean, atomic fp32 accumulate.
// NOTE: stores kv TRANSPOSED: kvT[e][d] (B-operand layout for out_mfma).
// ---------------------------------------------------------------------------
__global__ __launch_bounds__(256) void kv_partial(
    const __hip_bfloat16* __restrict__ kws, const float* __restrict__ x,
    float* __restrict__ kvT, float* __restrict__ kmean)
{
    __shared__ float kt[32][64];
    __shared__ float vt[32][64];
    const int t  = threadIdx.x;
    const int s  = blockIdx.x;       // N chunk 0..15
    const int bh = blockIdx.y;       // 0..63
    const int b  = bh >> 3, h = bh & 7;
    const int td = t >> 4, te = t & 15;
    const int kr = t >> 3;
    const int kc = (t & 7) * 8;
    const int vr = t >> 4;
    const int vc = (t & 15) * 4;

    const size_t base = (size_t)b * N_ * C_ + h * HD_;

    float acc[4][4];
    float ksum[4] = {0.f, 0.f, 0.f, 0.f};
#pragma unroll
    for (int i = 0; i < 4; i++)
#pragma unroll
        for (int j = 0; j < 4; j++) acc[i][j] = 0.f;

    const int nstart = s * (N_ / 16);
    for (int n0 = nstart; n0 < nstart + N_ / 16; n0 += 32) {
        uint4  ku = *(const uint4*)&kws[base + (size_t)(n0 + kr) * C_ + kc];
        float4 v0 = *(const float4*)&x[base + (size_t)(n0 + vr) * C_ + vc];
        float4 v1 = *(const float4*)&x[base + (size_t)(n0 + vr + 16) * C_ + vc];
        __syncthreads();
        kt[kr][kc + 0] = bf2f(ku.x & 0xffffu); kt[kr][kc + 1] = bf2f(ku.x >> 16);
        kt[kr][kc + 2] = bf2f(ku.y & 0xffffu); kt[kr][kc + 3] = bf2f(ku.y >> 16);
        kt[kr][kc + 4] = bf2f(ku.z & 0xffffu); kt[kr][kc + 5] = bf2f(ku.z >> 16);
        kt[kr][kc + 6] = bf2f(ku.w & 0xffffu); kt[kr][kc + 7] = bf2f(ku.w >> 16);
        *(float4*)&vt[vr][vc]      = v0;
        *(float4*)&vt[vr + 16][vc] = v1;
        __syncthreads();
#pragma unroll
        for (int nn = 0; nn < 32; nn++) {
            float4 kd = *(const float4*)&kt[nn][td * 4];
            float4 ve = *(const float4*)&vt[nn][te * 4];
            float kr4[4] = {kd.x, kd.y, kd.z, kd.w};
            float vr4[4] = {ve.x, ve.y, ve.z, ve.w};
#pragma unroll
            for (int i = 0; i < 4; i++)
#pragma unroll
                for (int j = 0; j < 4; j++) acc[i][j] += kr4[i] * vr4[j];
            ksum[0] += kd.x; ksum[1] += kd.y; ksum[2] += kd.z; ksum[3] += kd.w;
        }
    }

    // transposed store: kvT[e][d] += acc[i][j] where d=td*4+i, e=te*4+j
    float* kvp = kvT + (size_t)bh * HD_ * HD_;
#pragma unroll
    for (int i = 0; i < 4; i++)
#pragma unroll
        for (int j = 0; j < 4; j++)
            atomicAdd(&kvp[(te * 4 + j) * HD_ + td * 4 + i], acc[i][j]);
    if (te == 0) {
#pragma unroll
        for (int i = 0; i < 4; i++)
            atomicAdd(&kmean[bh * HD_ + td * 4 + i], ksum[i] * (1.0f / N_));
    }
}

// ---------------------------------------------------------------------------
// Kernel 3: out[b,n,h*64+e] = z[n] * (q @ kv)[n,e] + lepe(x)   via MFMA.
// 128 tokens x 64 cols per block; grid (N/128, B*H) = (64,64).
// qs/kvs bf16 in LDS with 72-short row stride (2-way bank pattern = free,
// 16B-aligned for ds_read_b128). Wave wv owns 32 tokens (2 bands of 16).
// ---------------------------------------------------------------------------
__global__ __launch_bounds__(256, 2) void out_mfma(
    const __hip_bfloat16* __restrict__ qws, const float* __restrict__ x,
    const float* __restrict__ kvT, const float* __restrict__ kmean,
    const float* __restrict__ lw, const float* __restrict__ lb,
    float* __restrict__ out)
{
    __shared__ __align__(16) unsigned short qs[128][72];   // q tokens x d
    __shared__ __align__(16) unsigned short kvs[64][72];   // kvT: e x d
    __shared__ float xs[130][68];                          // lepe halo tile
    __shared__ float zz[128];
    __shared__ float pz[128][2];
    __shared__ float kms[64];
    __shared__ float lw0[64], lw1[64], lw2[64], lbs[64];

    const int t  = threadIdx.x;
    const int n0 = blockIdx.x * 128;
    const int bh = blockIdx.y;
    const int b  = bh >> 3, h = bh & 7;

    // --- staging ---
    {   // q: 128x64 bf16 = 1024 x (8 shorts)
        const __hip_bfloat16* qp = qws + ((size_t)b * N_ + n0) * C_ + h * HD_;
        for (int i = t; i < 1024; i += 256) {
            const int r = i >> 3, c8 = (i & 7) * 8;
            uint4 u = *(const uint4*)&qp[(size_t)r * C_ + c8];
            *(uint4*)&qs[r][c8] = u;
        }
    }
    {   // kvT fp32 -> bf16 LDS, straight copy (already transposed in ws)
        const float* kvp = kvT + (size_t)bh * 4096;
        for (int i = t; i < 2048; i += 256) {
            const int e = i >> 5, d0 = (i & 31) * 2;
            float2 v = *(const float2*)&kvp[e * 64 + d0];
            *(unsigned*)&kvs[e][d0] = f2bf(v.x) | (f2bf(v.y) << 16);
        }
    }
    {   // x halo tile: 130 rows x 64 cols fp32
        for (int i = t; i < 130 * 16; i += 256) {
            const int r = i >> 4, c4 = (i & 15) * 4;
            const int n = n0 - 1 + r;
            float4 v = make_float4(0.f, 0.f, 0.f, 0.f);
            if (n >= 0 && n < N_)
                v = *(const float4*)&x[((size_t)b * N_ + n) * C_ + h * HD_ + c4];
            *(float4*)&xs[r][c4] = v;
        }
    }
    if (t < 64) {
        const int c = h * HD_ + t;
        lw0[t] = lw[c * 3 + 0];
        lw1[t] = lw[c * 3 + 1];
        lw2[t] = lw[c * 3 + 2];
        lbs[t] = lb[c];
        kms[t] = kmean[bh * HD_ + t];
    }
    __syncthreads();

    // --- z = 1/(q . kmean + eps), 2 threads per token ---
    {
        const int nn = t >> 1, d0 = (t & 1) * 32;
        float s = 0.f;
        for (int d = d0; d < d0 + 32; d++) s += bf2f(qs[nn][d]) * kms[d];
        pz[nn][t & 1] = s;
    }
    __syncthreads();
    if (t < 128) zz[t] = 1.0f / (pz[t][0] + pz[t][1] + 1e-6f);
    __syncthreads();

    // --- MFMA: wave wv -> tokens [wv*32, wv*32+32) ---
    const int wv = t >> 6, ln = t & 63;
    const int fr = ln & 15;
    const int fk = (ln >> 4) * 8;
    const int r0 = wv * 32;

    f32x4 acc[2][4];
#pragma unroll
    for (int bd = 0; bd < 2; bd++)
#pragma unroll
        for (int c = 0; c < 4; c++) acc[bd][c] = {0.f, 0.f, 0.f, 0.f};

    short8 af[2][2], bfr[4][2];
#pragma unroll
    for (int bd = 0; bd < 2; bd++)
#pragma unroll
        for (int kk = 0; kk < 2; kk++)
            af[bd][kk] = *(const short8*)&qs[r0 + bd * 16 + fr][kk * 32 + fk];
#pragma unroll
    for (int c = 0; c < 4; c++)
#pragma unroll
        for (int kk = 0; kk < 2; kk++)
            bfr[c][kk] = *(const short8*)&kvs[c * 16 + fr][kk * 32 + fk];
#pragma unroll
    for (int bd = 0; bd < 2; bd++)
#pragma unroll
        for (int c = 0; c < 4; c++)
#pragma unroll
            for (int kk = 0; kk < 2; kk++)
                acc[bd][c] = __builtin_amdgcn_mfma_f32_16x16x32_bf16(
                    af[bd][kk], bfr[c][kk], acc[bd][c], 0, 0, 0);

    // --- epilogue: *z + lepe, scalar stores (16-lane 64B segments) ---
    const int rb = (ln >> 4) * 4;
#pragma unroll
    for (int bd = 0; bd < 2; bd++) {
#pragma unroll
        for (int c = 0; c < 4; c++) {
            const int e = c * 16 + fr;
            const float w0 = lw0[e], w1 = lw1[e], w2 = lw2[e], bb = lbs[e];
#pragma unroll
            for (int r = 0; r < 4; r++) {
                const int nn = r0 + bd * 16 + rb + r;
                const float le = xs[nn][e] * w0 + xs[nn + 1][e] * w1
                               + xs[nn + 2][e] * w2 + bb;
                out[((size_t)b * N_ + n0 + nn) * C_ + h * HD_ + e] =
                    acc[bd][c][r] * zz[nn] + le;
            }
        }
    }
}

// ---------------------------------------------------------------------------
extern "C" void kernel_launch(void* const* d_in, const int* in_sizes, int n_in,
                              void* d_out, int out_size, void* d_ws, size_t ws_size,
                              hipStream_t stream)
{
    const float* x      = (const float*)d_in[0];
    const float* qk_w   = (const float*)d_in[1];
    const float* qk_b   = (const float*)d_in[2];
    const float* lepe_w = (const float*)d_in[3];
    const float* lepe_b = (const float*)d_in[4];
    float* out = (float*)d_out;

    // Workspace (135.3 MB):
    //   q  bf16 [M, C]        67.1 MB
    //   k  bf16 [M, C]        67.1 MB
    //   kvT f32 [64][64][64]   1 MB  (atomic-accum, transposed [e][d])
    //   kmean f32 [64][64]    16 KB
    char* ws = (char*)d_ws;
    __hip_bfloat16* qws = (__hip_bfloat16*)ws;
    __hip_bfloat16* kws = qws + (size_t)M_ * C_;
    float* kvT   = (float*)(ws + 2 * (size_t)M_ * C_ * sizeof(__hip_bfloat16));
    float* kmean = kvT + (size_t)64 * HD_ * HD_;

    hipMemsetAsync(kvT, 0, (size_t)(64 * HD_ * HD_ + 64 * HD_) * sizeof(float),
                   stream);
    gemm_qk_mfma<<<4096, 256, 0, stream>>>(x, qk_w, qk_b, qws, kws);
    kv_partial<<<dim3(16, 64), 256, 0, stream>>>(kws, x, kvT, kmean);
    out_mfma<<<dim3(N_ / 128, B_ * H_), 256, 0, stream>>>(
        qws, x, kvT, kmean, lepe_w, lepe_b, out);
}